// Round 5
// baseline (443.982 us; speedup 1.0000x reference)
//
#include <hip/hip_runtime.h>

// BuildingModule: B=8192 sequential chains, T=1024 steps, u:(B,T,8) f32, out:(B,T,3) f32.
//
// R8: break the serial transcendental chain. Evidence: R3/R6/R7 (three
// different memory structures: per-step LDS reads, hoisted reads, register
// double-buffer) all measure 161-163 us -> the bound is invariant to memory
// scheduling. Per wave-step: 378 cy measured vs ~86 cy issue. The only shared
// structure is the recurrence chain  X -> v_rcp -> fma(z) -> v_exp -> mul,
// ~132 cy/step if trans dependent latency is ~60 cy. Fix: maintain the
// inverse incrementally, I_k *= exp2(-z_k) (negate folds into v_exp src
// modifier), removing rcp from the chain: z -> exp2 -> mul ~ 75 cy/step.
// Accuracy: I drifts ~2 ulp/step; refreshed exactly via I = rcp(X) at the
// END of every 8-step half (rcp latency covered by inter-half fold/prefetch
// code, off the critical path). Max drift 8 steps (~2e-6 rel) -> dz ~ 2e-7
// per step, below the exp2 ulp noise already present.
//
// Memory structure unchanged from R7 (verified correct): 16 lanes/chain,
// 2 waves/SIMD, LDS double-buffered folded rows (E0,G0',G1',G2'), register
// double-buffered halves, global prefetch one superblock ahead,
// wave-synchronous (no barriers), per-lane own-u0 masking.

#if __has_builtin(__builtin_amdgcn_exp2f)
#define EXP2F(x) __builtin_amdgcn_exp2f(x)
#else
#define EXP2F(x) __expf((x) * 0.69314718056f)
#endif

namespace {
constexpr int T = 1024;
constexpr int SB = 16;                 // rows per superblock = lanes per chain
constexpr int NSB = T / SB;            // 64 superblocks
constexpr float LOG2E = 1.4426950408889634f;
constexpr int CH_STRIDE = 132;         // floats per chain region: 2 bufs * 16 slots * 4 + 4 pad
}

__device__ __forceinline__ float rfl(float x) {
    return __int_as_float(__builtin_amdgcn_readfirstlane(__float_as_int(x)));
}

__global__ __launch_bounds__(256, 2) void bm_fwd(
    const float* __restrict__ x0p,   // (B,3)
    const float* __restrict__ up,    // (B,T,8)
    const float* __restrict__ lamp,  // (14)
    float* __restrict__ outp)        // (B,T,3)
{
    // 16 chains/WG * 528B = 8448B
    __shared__ float lds[16 * CH_STRIDE];

    const int tid   = blockIdx.x * 256 + threadIdx.x;
    const int chain = tid >> 4;            // global chain id
    const int l     = tid & 15;            // lane-in-chain = row phase
    float* __restrict__ region = lds + (threadIdx.x >> 4) * CH_STRIDE;

    // lam -> exponentials (uniform; precise expf once per thread, then SGPR'd)
    float e[14];
#pragma unroll
    for (int i = 0; i < 14; ++i) e[i] = expf(lamp[i]);

    // H/C in log2 domain, folded into every coefficient; wave-uniform -> SGPR
    const float hc0 = (60.0f / 10665991.0f) * LOG2E;
    const float hc1 = (60.0f / 27000000.0f) * LOG2E;
    const float hc2 = (60.0f / 7953253.0f) * LOG2E;
    const float F12_0 = rfl(hc0 * e[0]), F12_1 = rfl(hc1 * e[0]);
    const float F23_1 = rfl(hc1 * e[1]), F23_2 = rfl(hc2 * e[1]);
    const float hce0 = rfl(hc0 * e[2]),  hce1 = rfl(hc1 * e[3]),  hce2 = rfl(hc2 * e[4]);
    const float ss0  = rfl(hc0 * e[5]),  ss1  = rfl(hc1 * e[6]),  ss2  = rfl(hc2 * e[7]);
    const float sh0  = rfl(hc0 * e[8]),  sh1  = rfl(hc1 * e[9]),  sh2  = rfl(hc2 * e[10]);
    const float sc0  = rfl(hc0 * e[11]), sc1  = rfl(hc1 * e[12]), sc2  = rfl(hc2 * e[13]);
    const float g0c = rfl(-hce0 - F12_0);
    const float g1c = rfl(-hce1 - F12_1 - F23_1);
    const float g2c = rfl(-hce2 - F23_2);
    const float r10 = rfl(hce1 / hce0);    // E1 = r10 * E0
    const float r20 = rfl(hce2 / hce0);    // E2 = r20 * E0

    float X0 = x0p[3 * chain + 0];
    float X1 = x0p[3 * chain + 1];
    float X2 = x0p[3 * chain + 2];
    // incrementally-maintained inverses (refreshed every 8 steps)
    float I0 = __builtin_amdgcn_rcpf(X0);
    float I1 = __builtin_amdgcn_rcpf(X1);
    float I2 = __builtin_amdgcn_rcpf(X2);

    const float4* __restrict__ ub = (const float4*)(up + (size_t)chain * (T * 8));
    float* __restrict__ ob = outp + (size_t)chain * (T * 3);

    // fold my row -> (E0, G0', G1', G2'); write 16B to my slot in buffer par
    auto fold_write = [&](int par, const float4& r0, const float4& r1) -> float {
        const float E0 = hce0 * r0.x;
        const float G0 = fmaf(sc0, r1.y, fmaf(sh0, r0.z, fmaf(ss0, r0.y, g0c)));
        const float G1 = fmaf(sc1, r1.z, fmaf(sh1, r0.w, fmaf(ss1, r0.y, g1c)));
        const float G2 = fmaf(sc2, r1.w, fmaf(sh2, r1.x, fmaf(ss2, r0.y, g2c)));
        *(float4*)(region + par * 64 + (l << 2)) = make_float4(E0, G0, G1, G2);
        return r0.x;
    };

    // issue 8 broadcast reads (slots half*8 .. half*8+7 of buffer par)
    auto read_half = [&](float4 (&H)[8], int par, int half) {
        const float* base = region + par * 64 + half * 32;
#pragma unroll
        for (int i = 0; i < 8; ++i) H[i] = *(const float4*)(base + (i << 2));
    };

    float O0 = 0.0f, O1 = 0.0f, O2 = 0.0f;

    // 8 steps from a register-held half; base_i = global step index of H[0].
    // Serial chain per step: fma(z) -> exp2 -> mul (~75cy), rcp NOT in chain.
    // Ends with an exact inverse refresh for the next half (off critical path).
    auto compute_half = [&](const float4 (&H)[8], int base_i) {
#pragma unroll
        for (int ii = 0; ii < 8; ++ii) {
            const float4 r = H[ii];
            if (l == base_i + ii) { O0 = X0; O1 = X1; O2 = X2; }  // state BEFORE this step
            // p_k depend only on X and broadcast E0
            const float p0 = fmaf(F12_0, X1, r.x);
            const float p1 = fmaf(F12_1, X0, fmaf(F23_1, X2, r10 * r.x));
            const float p2 = fmaf(F23_2, X1, r20 * r.x);
            const float z0 = fmaf(I0, p0, r.y);   // r.y = G0'
            const float z1 = fmaf(I1, p1, r.z);   // r.z = G1'
            const float z2 = fmaf(I2, p2, r.w);   // r.w = G2'
            X0 *= EXP2F(z0);
            X1 *= EXP2F(z1);
            X2 *= EXP2F(z2);
            I0 *= EXP2F(-z0);                     // neg folds into v_exp src modifier
            I1 *= EXP2F(-z1);
            I2 *= EXP2F(-z2);
        }
        // exact refresh for the next half; latency covered by inter-half code
        I0 = __builtin_amdgcn_rcpf(X0);
        I1 = __builtin_amdgcn_rcpf(X1);
        I2 = __builtin_amdgcn_rcpf(X2);
    };

    float4 H0[8], H1[8];   // register double-buffer of broadcast rows
    float4 pf0, pf1;       // raw u row one superblock ahead, in flight
    float u0_cur;          // my own row's u0 for the CURRENT superblock

    // prologue: load+fold rows of sb=0 into buf 0; H0 <- its first half;
    // prefetch rows of sb=1
    {
        const float4* s = ub + (size_t)(l * 2);
        float4 t0 = s[0], t1 = s[1];
        u0_cur = fold_write(0, t0, t1);
        read_half(H0, 0, 0);
        __builtin_amdgcn_sched_barrier(0);
        const float4* p = ub + (size_t)((SB + l) * 2);
        pf0 = p[0]; pf1 = p[1];
    }

    // invariant entering iteration sb: buf[sb&1] holds sb's 16 folded rows,
    // H0 holds sb's first half (reads complete or in flight), pf holds raw
    // rows of sb+1, u0_cur is my u0 for sb.
    for (int sb = 0; sb < NSB; ++sb) {
        const int par = sb & 1;

        // issue reads for current sb's second half
        read_half(H1, par, 1);
        __builtin_amdgcn_sched_barrier(0);

        // fold prefetched rows of sb+1 into the other buffer
        // (sb=NSB-1: pf holds clamped dup; lands in the never-computed buffer)
        const float u0_next = fold_write(par ^ 1, pf0, pf1);

        // prefetch rows of sb+2 (clamped) -> in flight for a full superblock
        {
            const int jj = (sb + 2 < NSB) ? (sb + 2) : (NSB - 1);
            const float4* p = ub + (size_t)((jj * SB + l) * 2);
            pf0 = p[0]; pf1 = p[1];
        }
        __builtin_amdgcn_sched_barrier(0);

        // steps 0-7 from H0 (covers H1's lgkm)
        compute_half(H0, 0);

        // issue reads for NEXT sb's first half (after the ds_write above;
        // same-wave in-order DS pipe orders write->read)
        read_half(H0, par ^ 1, 0);
        __builtin_amdgcn_sched_barrier(0);

        // steps 8-15 from H1 (covers H0's lgkm)
        compute_half(H1, 8);

        // store my output row t = sb*16 + l (state BEFORE step l), masked by
        // my OWN u0; t==0 is x0, never masked.
        const int t = sb * SB + l;
        const bool bad = (u0_cur < 1e-6f) && (t != 0);
        float3 o;
        o.x = bad ? -1.0f : O0;
        o.y = bad ? -1.0f : O1;
        o.z = bad ? -1.0f : O2;
        *(float3*)(ob + (size_t)t * 3) = o;

        u0_cur = u0_next;
    }
}

extern "C" void kernel_launch(void* const* d_in, const int* in_sizes, int n_in,
                              void* d_out, int out_size, void* d_ws, size_t ws_size,
                              hipStream_t stream) {
    const float* x0  = (const float*)d_in[0];   // (B,3)
    const float* u   = (const float*)d_in[1];   // (B,T,8)
    const float* lam = (const float*)d_in[2];   // (14)
    float* out = (float*)d_out;                 // (B,T,3)

    const int B = in_sizes[0] / 3;              // 8192
    const int threads = B * 16;                 // 16 lanes per chain
    dim3 grid(threads / 256), block(256);
    hipLaunchKernelGGL(bm_fwd, grid, block, 0, stream, x0, u, lam, out);
}

// Round 6
// 429.796 us; speedup vs baseline: 1.0330x; 1.0330x over previous
//
#include <hip/hip_runtime.h>

// BuildingModule: B=8192 sequential chains, T=1024 steps, u:(B,T,8) f32, out:(B,T,3) f32.
//
// R9: remove ALL transcendentals from the step loop. Evidence chain:
//  - R3/R6/R7 (different memory structures) all ~380 cy/wave-step wall.
//  - R7=R6: register-held vs per-step LDS reads -> memory scheduling not the wall.
//  - R8=R7: fma-chain topology change (rcp off chain) -> fma chain not the wall.
//  - 2 waves vs 1 wave: same time, 2x VALUBusy -> latency-bound; issue ~100cy.
//  The only structure common to all variants: 6 v_exp/v_rcp per step on the
//  recurrence path. Hypothesis: trans dependent latency (incl. hazards) is the
//  ~380cy wall. Test: replace exp2 with a degree-5 even/odd polynomial.
//
// Numerics: absmax 65536 from x~280 over 1024 steps -> per-step growth
// ~1.0055 -> |z| ~ 0.008 typical, <=~0.1 conservative. Taylor-5 of 2^z at
// |z|<=0.12 has truncation < 1e-9 rel (f32 rounding dominates). Even/odd
// split yields BOTH 2^z and 2^-z from one evaluation:
//   E = 1 + c2 z^2 + c4 z^4,  O = z*(c1 + c3 z^2 + c5 z^4)
//   X *= (E+O);  I *= (E-O)      // I = running 1/X, R8 scheme
// P(z)*P(-z) = E^2-O^2 = 1 + O(1e-12), plus ~0.5ulp/step rounding drift on I;
// exact rcp refresh once per superblock (off critical path, 3 rcp / 16 steps).
//
// Memory structure = R6 (simplest of the three proven-equal variants):
// 16 lanes/chain, 2 waves/SIMD, LDS double-buffered folded rows
// (E0,G0',G1',G2'), per-step 16B same-address broadcast read (0 conflicts
// measured), global prefetch one superblock ahead, wave-synchronous (16
// lanes within one wave, in-order DS pipe), per-lane own-u0 masking.
// Same verified algebra: z_k = I_k*p_k + G_k', p_k = F*X_nb + E_k, -F in G'.

namespace {
constexpr int T = 1024;
constexpr int SB = 16;                 // rows per superblock = lanes per chain
constexpr int NSB = T / SB;            // 64 superblocks
constexpr float LOG2E = 1.4426950408889634f;
constexpr int CH_STRIDE = 132;         // floats per chain region: 2 bufs * 16 slots * 4 + 4 pad
// Taylor coefficients of 2^z = e^{z ln2}: c_k = (ln2)^k / k!
constexpr float PC1 = 0.69314718055994531f;
constexpr float PC2 = 0.24022650695910072f;
constexpr float PC3 = 0.05550410866482158f;
constexpr float PC4 = 0.00961812910762848f;
constexpr float PC5 = 0.00133335581464284f;
}

__device__ __forceinline__ float rfl(float x) {
    return __int_as_float(__builtin_amdgcn_readfirstlane(__float_as_int(x)));
}

__global__ __launch_bounds__(256, 2) void bm_fwd(
    const float* __restrict__ x0p,   // (B,3)
    const float* __restrict__ up,    // (B,T,8)
    const float* __restrict__ lamp,  // (14)
    float* __restrict__ outp)        // (B,T,3)
{
    // 16 chains/WG * 528B = 8448B
    __shared__ float lds[16 * CH_STRIDE];

    const int tid   = blockIdx.x * 256 + threadIdx.x;
    const int chain = tid >> 4;            // global chain id
    const int l     = tid & 15;            // lane-in-chain = row phase
    float* __restrict__ region = lds + (threadIdx.x >> 4) * CH_STRIDE;

    // lam -> exponentials (uniform; precise expf once per thread, then SGPR'd)
    float e[14];
#pragma unroll
    for (int i = 0; i < 14; ++i) e[i] = expf(lamp[i]);

    // H/C in log2 domain, folded into every coefficient; wave-uniform -> SGPR
    const float hc0 = (60.0f / 10665991.0f) * LOG2E;
    const float hc1 = (60.0f / 27000000.0f) * LOG2E;
    const float hc2 = (60.0f / 7953253.0f) * LOG2E;
    const float F12_0 = rfl(hc0 * e[0]), F12_1 = rfl(hc1 * e[0]);
    const float F23_1 = rfl(hc1 * e[1]), F23_2 = rfl(hc2 * e[1]);
    const float hce0 = rfl(hc0 * e[2]),  hce1 = rfl(hc1 * e[3]),  hce2 = rfl(hc2 * e[4]);
    const float ss0  = rfl(hc0 * e[5]),  ss1  = rfl(hc1 * e[6]),  ss2  = rfl(hc2 * e[7]);
    const float sh0  = rfl(hc0 * e[8]),  sh1  = rfl(hc1 * e[9]),  sh2  = rfl(hc2 * e[10]);
    const float sc0  = rfl(hc0 * e[11]), sc1  = rfl(hc1 * e[12]), sc2  = rfl(hc2 * e[13]);
    const float g0c = rfl(-hce0 - F12_0);
    const float g1c = rfl(-hce1 - F12_1 - F23_1);
    const float g2c = rfl(-hce2 - F23_2);
    const float r10 = rfl(hce1 / hce0);    // E1 = r10 * E0
    const float r20 = rfl(hce2 / hce0);    // E2 = r20 * E0

    float X0 = x0p[3 * chain + 0];
    float X1 = x0p[3 * chain + 1];
    float X2 = x0p[3 * chain + 2];
    // running inverses, refreshed exactly once per superblock
    float I0 = __builtin_amdgcn_rcpf(X0);
    float I1 = __builtin_amdgcn_rcpf(X1);
    float I2 = __builtin_amdgcn_rcpf(X2);

    const float4* __restrict__ ub = (const float4*)(up + (size_t)chain * (T * 8));
    float* __restrict__ ob = outp + (size_t)chain * (T * 3);

    // fold my row -> (E0, G0', G1', G2'); write 16B to my slot in buffer par
    auto fold_write = [&](int par, const float4& r0, const float4& r1) -> float {
        const float E0 = hce0 * r0.x;
        const float G0 = fmaf(sc0, r1.y, fmaf(sh0, r0.z, fmaf(ss0, r0.y, g0c)));
        const float G1 = fmaf(sc1, r1.z, fmaf(sh1, r0.w, fmaf(ss1, r0.y, g1c)));
        const float G2 = fmaf(sc2, r1.w, fmaf(sh2, r1.x, fmaf(ss2, r0.y, g2c)));
        *(float4*)(region + par * 64 + (l << 2)) = make_float4(E0, G0, G1, G2);
        return r0.x;
    };

    // one poly step for one component: X *= 2^z, I *= 2^-z, no trans ops
    auto pstep = [](float z, float& X, float& I) {
        const float z2 = z * z;
        const float ev = fmaf(fmaf(PC4, z2, PC2), z2, 1.0f);
        const float od = z * fmaf(fmaf(PC5, z2, PC3), z2, PC1);
        X *= (ev + od);
        I *= (ev - od);
    };

    float4 pf0, pf1;     // raw u row for superblock sb+1, in flight
    float u0_cur;        // my own row's u0 for the CURRENT superblock

    // prologue: load+fold rows of sb=0 into buf 0; prefetch rows of sb=1
    {
        const float4* s = ub + (size_t)(l * 2);
        float4 t0 = s[0], t1 = s[1];
        u0_cur = fold_write(0, t0, t1);
        const float4* p = ub + (size_t)((SB + l) * 2);
        pf0 = p[0]; pf1 = p[1];
    }

    for (int sb = 0; sb < NSB; ++sb) {
        const int par = sb & 1;

        // fold prefetched rows of sb+1 into the other buffer
        // (sb=NSB-1: clamped dup lands in the never-read buffer -> harmless)
        const float u0_next = fold_write(par ^ 1, pf0, pf1);

        // prefetch rows of sb+2 (clamped) -> in flight for a full superblock
        {
            const int jj = (sb + 2 < NSB) ? (sb + 2) : (NSB - 1);
            const float4* p = ub + (size_t)((jj * SB + l) * 2);
            pf0 = p[0]; pf1 = p[1];
        }

        // 16 steps from buffer par (per-step 16B same-address broadcast read)
        float O0 = 0.0f, O1 = 0.0f, O2 = 0.0f;
        const float* rdbase = region + par * 64;
#pragma unroll
        for (int i = 0; i < SB; ++i) {
            const float4 r = *(const float4*)(rdbase + (i << 2));
            if (l == i) { O0 = X0; O1 = X1; O2 = X2; }   // state BEFORE step i
            const float E0 = r.x;
            // p_k depend only on X and broadcast E0
            const float p0 = fmaf(F12_0, X1, E0);
            const float p1 = fmaf(F12_1, X0, fmaf(F23_1, X2, r10 * E0));
            const float p2 = fmaf(F23_2, X1, r20 * E0);
            const float z0 = fmaf(I0, p0, r.y);   // r.y = G0'
            const float z1 = fmaf(I1, p1, r.z);   // r.z = G1'
            const float z2 = fmaf(I2, p2, r.w);   // r.w = G2'
            pstep(z0, X0, I0);
            pstep(z1, X1, I1);
            pstep(z2, X2, I2);
        }

        // exact inverse refresh (3 rcp / 16 steps, off the critical path:
        // next loop's first z consumes I ~20 instrs later)
        I0 = __builtin_amdgcn_rcpf(X0);
        I1 = __builtin_amdgcn_rcpf(X1);
        I2 = __builtin_amdgcn_rcpf(X2);

        // store my output row t = sb*16 + l (state BEFORE step l), masked by
        // my OWN u0; t==0 is x0, never masked.
        const int t = sb * SB + l;
        const bool bad = (u0_cur < 1e-6f) && (t != 0);
        float3 o;
        o.x = bad ? -1.0f : O0;
        o.y = bad ? -1.0f : O1;
        o.z = bad ? -1.0f : O2;
        *(float3*)(ob + (size_t)t * 3) = o;

        u0_cur = u0_next;
    }
}

extern "C" void kernel_launch(void* const* d_in, const int* in_sizes, int n_in,
                              void* d_out, int out_size, void* d_ws, size_t ws_size,
                              hipStream_t stream) {
    const float* x0  = (const float*)d_in[0];   // (B,3)
    const float* u   = (const float*)d_in[1];   // (B,T,8)
    const float* lam = (const float*)d_in[2];   // (14)
    float* out = (float*)d_out;                 // (B,T,3)

    const int B = in_sizes[0] / 3;              // 8192
    const int threads = B * 16;                 // 16 lanes per chain
    dim3 grid(threads / 256), block(256);
    hipLaunchKernelGGL(bm_fwd, grid, block, 0, stream, x0, u, lam, out);
}